// Round 2
// 374.318 us; speedup vs baseline: 1.0601x; 1.0601x over previous
//
#include <hip/hip_runtime.h>
#include <math.h>

#ifndef M_PI
#define M_PI 3.14159265358979323846
#endif

#define T_LEN 4096
#define M_LEN 2048   // T/2, complex FFT length
#define NFREQ 2049   // T/2 + 1
#define KM 8         // modes
#define LI 8         // iterations
#define CD 16        // channels

// Stockham radix-2 DIF, N=2048, 11 stages, ping-pong a<->b.
// sign = -1: forward DFT (e^{-i...}); sign = +1: unnormalized inverse.
// Caller must __syncthreads() after filling `a` before calling.
// Returns pointer to buffer holding the natural-order result.
template <int NT>
__device__ __forceinline__ float2* fft2048(float2* a, float2* b, int tid, float sign) {
    float2* src = a;
    float2* dst = b;
    int l = 1024;
    #pragma unroll 1
    for (int s = 0; s < 11; ++s) {
        float piol = sign * (float)M_PI / (float)l;
        #pragma unroll
        for (int ii = 0; ii < 1024 / NT; ++ii) {
            int i = tid + ii * NT;
            int j = i >> s;             // butterfly group
            float2 A = src[i];
            float2 B = src[i + 1024];
            float ang = piol * (float)j;
            float sw, cw;
            __sincosf(ang, &sw, &cw);
            float2 sum = make_float2(A.x + B.x, A.y + B.y);
            float2 dif = make_float2(A.x - B.x, A.y - B.y);
            float2 tw = make_float2(dif.x * cw - dif.y * sw, dif.x * sw + dif.y * cw);
            int p = i + (j << s);       // i + j*m, m = 1<<s
            dst[p] = sum;
            dst[p + (1 << s)] = tw;
        }
        __syncthreads();
        float2* t = src; src = dst; dst = t;
        l >>= 1;
    }
    return src;  // after final swap, src holds the result
}

// K1: one block per row (b,c). Forward rfft + L x K Jacobi iteration per bin,
// write u_final spectra to ws, coalesced, layout [(b*8+k)*16+c][f].
// (UNCHANGED this round.)
__global__ void __launch_bounds__(512)
k_fwd_iter(const float* __restrict__ x,
           const float* __restrict__ log_alpha,
           const float* __restrict__ raw_tau,
           const float* __restrict__ raw_omega,
           float2* __restrict__ u_ws)
{
    __shared__ float2 bufA[M_LEN];
    __shared__ float2 bufB[M_LEN];
    __shared__ float s_2a[LI * KM];
    __shared__ float s_tau[LI];
    __shared__ float s_om[KM];

    const int tid = threadIdx.x;
    const int row = blockIdx.x;       // b*16 + c
    const int b = row >> 4;
    const int c = row & 15;

    if (tid < LI * KM) s_2a[tid] = 2.0f * __expf(log_alpha[tid]);
    if (tid < LI)      s_tau[tid] = log1pf(__expf(raw_tau[tid]));     // softplus
    if (tid < KM)      s_om[tid]  = 0.5f / (1.0f + __expf(-raw_omega[tid]));  // 0.5*sigmoid

    const float* xr = x + (size_t)b * T_LEN * CD + c;
    #pragma unroll
    for (int q = 0; q < 4; ++q) {
        int n = tid + q * 512;
        float e = xr[(size_t)(2 * n) * CD];
        float o = xr[(size_t)(2 * n + 1) * CD];
        bufA[n] = make_float2(e, o);
    }
    __syncthreads();

    float2* Z = fft2048<512>(bufA, bufB, tid, -1.0f);   // ends in bufB

    const size_t sb = (size_t)(b * (KM * CD) + c);      // slice base (k stride = CD)

    for (int f = tid; f < NFREQ; f += 512) {
        float2 Zk = Z[f & (M_LEN - 1)];
        float2 Zm = Z[(M_LEN - f) & (M_LEN - 1)];
        float2 E = make_float2(0.5f * (Zk.x + Zm.x), 0.5f * (Zk.y - Zm.y));
        float2 D = make_float2(0.5f * (Zk.x - Zm.x), 0.5f * (Zk.y + Zm.y));
        float2 O = make_float2(D.y, -D.x);
        float ang = -2.0f * (float)M_PI * (float)f / (float)T_LEN;
        float sw, cw;
        __sincosf(ang, &sw, &cw);
        float fhx = E.x + cw * O.x - sw * O.y;
        float fhy = E.y + cw * O.y + sw * O.x;

        float freq = (float)f * (0.5f / (float)M_LEN);
        float dd[KM];
        #pragma unroll
        for (int k = 0; k < KM; ++k) {
            float d = freq - s_om[k];
            dd[k] = d * d;
        }

        float2 u[KM];
        #pragma unroll
        for (int k = 0; k < KM; ++k) u[k] = make_float2(0.f, 0.f);
        float lamx = 0.f, lamy = 0.f;

        #pragma unroll
        for (int l = 0; l < LI; ++l) {
            float usx = 0.f, usy = 0.f;
            #pragma unroll
            for (int k = 0; k < KM; ++k) { usx += u[k].x; usy += u[k].y; }
            float bx = fhx - usx + 0.5f * lamx;
            float by = fhy - usy + 0.5f * lamy;
            float sx = 0.f, sy = 0.f;
            #pragma unroll
            for (int k = 0; k < KM; ++k) {
                float den = fmaf(s_2a[l * KM + k], dd[k], 1.0f);
                float r = __builtin_amdgcn_rcpf(den);
                float ux = (bx + u[k].x) * r;
                float uy = (by + u[k].y) * r;
                u[k].x = ux; u[k].y = uy;
                sx += ux; sy += uy;
            }
            lamx += s_tau[l] * (fhx - sx);
            lamy += s_tau[l] * (fhy - sy);
        }

        #pragma unroll
        for (int k = 0; k < KM; ++k) {
            u_ws[(sb + (size_t)k * CD) * NFREQ + f] = u[k];
        }
    }
}

// K2: one block per (b,k). 16 inverse rffts, batched 2 channels per FFT pass.
//  - irfft repack computed directly from global (j and 2048-j derived from the
//    same two loads), removing the staging buffer and its barrier
//  - readout of the previous pass folded before the fill barrier
//  - one __sincosf per stage shared across both channels (2x fewer than r0)
// Static LDS = 2*2*2048*8 = 65536 B (exactly the 64 KB static-shared envelope;
// the 72 KB variant with an LDS twiddle table crashed at launch in r1).
// Barriers/block: 224 -> 96. Per-stage ILP: 1 butterfly -> 2.
__global__ void __launch_bounds__(1024)
k_inv(const float2* __restrict__ u_ws, float* __restrict__ out)
{
    __shared__ __align__(16) float2 buf[2][2][M_LEN];   // [ch][pingpong A/B][n]

    const int tid = threadIdx.x;
    const int bk = blockIdx.x;        // b*8 + k

    float val[CD][4];                 // [c][t offset] staged for coalesced stores
    const float sc = 1.0f / (float)M_LEN;

    #pragma unroll 1
    for (int cp = 0; cp < 8; ++cp) {
        // ---- readout of previous pass (result sits in B buffers) ----
        if (cp > 0) {
            #pragma unroll
            for (int ch = 0; ch < 2; ++ch) {
                int c = 2 * (cp - 1) + ch;
                float4 z = *(const float4*)&buf[ch][1][2 * tid];
                val[c][0] = z.x; val[c][1] = z.y; val[c][2] = z.z; val[c][3] = z.w;
            }
        }

        // ---- fill A buffers: irfft even/odd repack straight from global ----
        // thread j produces buf[j] AND buf[2048-j] from the same pair of loads:
        //   E' = (Ex,-Ey), D' = (-Dx,Dy), W' = (-cw,sw)  =>  O' = (Ox,-Oy)
        #pragma unroll
        for (int ch = 0; ch < 2; ++ch) {
            int c = 2 * cp + ch;
            const float2* sp = u_ws + (size_t)(bk * CD + c) * NFREQ;
            int j = tid;
            float2 Xj = sp[j];
            float2 Xm = sp[M_LEN - j];          // j=0 -> Nyquist (2048)
            float Ex = 0.5f * (Xj.x + Xm.x), Ey = 0.5f * (Xj.y - Xm.y);
            float Dx = 0.5f * (Xj.x - Xm.x), Dy = 0.5f * (Xj.y + Xm.y);
            float ang = (2.0f * (float)M_PI / (float)T_LEN) * (float)j;
            float sw, cw;
            __sincosf(ang, &sw, &cw);
            float Ox = cw * Dx - sw * Dy;
            float Oy = cw * Dy + sw * Dx;
            buf[ch][0][j] = make_float2((Ex - Oy) * sc, (Ey + Ox) * sc);
            if (j > 0) {
                buf[ch][0][M_LEN - j] = make_float2((Ex + Oy) * sc, (Ox - Ey) * sc);
            } else {
                // index 1024 pairs with itself: W=i -> out = (X.x, -X.y)/M
                float2 Xq = sp[1024];
                buf[ch][0][1024] = make_float2(Xq.x * sc, -Xq.y * sc);
            }
        }
        // One barrier orders: fill-writes(A) vs stage0-reads(A), AND
        // prev readout-reads(B) vs stage0-writes(B).
        __syncthreads();

        // ---- 11 Stockham stages, 2 channels per thread, shared twiddle ----
        float2* s0 = buf[0][0]; float2* d0 = buf[0][1];
        float2* s1 = buf[1][0]; float2* d1 = buf[1][1];
        #pragma unroll 1
        for (int s = 0; s < 11; ++s) {
            const int i = tid;
            const int j = i >> s;
            const int m = 1 << s;
            const int p = i + (j << s);
            // inverse transform: ang = +pi*(j<<s)/1024
            float ang = ((float)M_PI / 1024.0f) * (float)(j << s);
            float sw, cw;
            __sincosf(ang, &sw, &cw);
            {
                float2 A = s0[i], B = s0[i + 1024];
                float2 sum = make_float2(A.x + B.x, A.y + B.y);
                float2 dif = make_float2(A.x - B.x, A.y - B.y);
                float2 t = make_float2(dif.x * cw - dif.y * sw,
                                       dif.x * sw + dif.y * cw);
                d0[p] = sum;
                d0[p + m] = t;
            }
            {
                float2 A = s1[i], B = s1[i + 1024];
                float2 sum = make_float2(A.x + B.x, A.y + B.y);
                float2 dif = make_float2(A.x - B.x, A.y - B.y);
                float2 t = make_float2(dif.x * cw - dif.y * sw,
                                       dif.x * sw + dif.y * cw);
                d1[p] = sum;
                d1[p + m] = t;
            }
            __syncthreads();
            float2* t0 = s0; s0 = d0; d0 = t0;
            float2* t1 = s1; s1 = d1; d1 = t1;
        }
        // 11 swaps (odd) -> results in buf[ch][1]; A buffers free to refill.
    }

    // ---- final readout (pass 7) ----
    #pragma unroll
    for (int ch = 0; ch < 2; ++ch) {
        int c = 14 + ch;
        float4 z = *(const float4*)&buf[ch][1][2 * tid];
        val[c][0] = z.x; val[c][1] = z.y; val[c][2] = z.z; val[c][3] = z.w;
    }

    // Each thread owns out[b, k, 4*tid .. 4*tid+3, 0..15]: contiguous 64 floats.
    float4* op = (float4*)(out + ((size_t)bk * T_LEN + (size_t)(4 * tid)) * CD);
    #pragma unroll
    for (int r = 0; r < 4; ++r) {
        #pragma unroll
        for (int g = 0; g < 4; ++g) {
            op[r * 4 + g] = make_float4(val[4 * g + 0][r], val[4 * g + 1][r],
                                        val[4 * g + 2][r], val[4 * g + 3][r]);
        }
    }
}

extern "C" void kernel_launch(void* const* d_in, const int* in_sizes, int n_in,
                              void* d_out, int out_size, void* d_ws, size_t ws_size,
                              hipStream_t stream) {
    const float* x         = (const float*)d_in[0];
    const float* log_alpha = (const float*)d_in[1];
    const float* raw_tau   = (const float*)d_in[2];
    const float* raw_omega = (const float*)d_in[3];
    float* out = (float*)d_out;
    float2* u_ws = (float2*)d_ws;   // needs 8192 * 2049 * 8 B = 134.3 MB

    k_fwd_iter<<<dim3(64 * CD), dim3(512), 0, stream>>>(x, log_alpha, raw_tau,
                                                        raw_omega, u_ws);
    k_inv<<<dim3(64 * KM), dim3(1024), 0, stream>>>(u_ws, out);
}